// Round 4
// baseline (446.308 us; speedup 1.0000x reference)
//
#include <hip/hip_runtime.h>

// LabelWiseMLC: out[b,l] = sigmoid(dot(doc_rep[b,l,:], W[l,:]) + bias[l])
// B=128, L=512, I=1024, fp32.
//
// v5: FORENSIC ROUND — not an optimization. Four structurally different
// kernels (strided reg-W, deep pipeline, contiguous stream, nt-ablation)
// all graded 330-352 us, and our kernel has never appeared in the rocprof
// top-5 (all five slots are ~161us 1-GiB harness poison fills) -> we have
// no direct counters for it. This round repeats the streaming phase 4x
// INSIDE one dispatch so the kernel exceeds 160 us and enters the top-5,
// exposing its true hbm_gbps / FETCH_SIZE / VALUBusy / OccupancyPercent.
//
// Correctness: the 4 passes are bit-identical; pairwise sum
// ((a0+a1)+(a2+a3)) = 4*a exactly (power-of-2 fp), then *0.25f exact ->
// output identical to a single pass (absmax 0). Inline-asm "+s" laundering
// of the base pointers between passes blocks CSE/LICM of the repeated
// loads. nt loads (no-allocate) force each pass to re-fetch from HBM, so
// dispatch_dur ~= 4*T. FETCH_SIZE ~= 4 x 268 MB verifies that assumption.
//
// Structure otherwise identical to v3: block = (b, lg) reads a contiguous
// 32-KB doc chunk; W (2 MB) L2-resident; folded butterfly + LDS combine.

#define B_DIM 128
#define L_DIM 512
#define I_DIM 1024
#define LG 8  // labels per block

typedef float vfloat4 __attribute__((ext_vector_type(4)));

__global__ __launch_bounds__(256) void labelwise_mlc_kernel(
    const float* __restrict__ doc,   // (B, L, I)
    const float* __restrict__ W,     // (L, I)
    const float* __restrict__ bias,  // (L,)
    float* __restrict__ out)         // (B, L)
{
    const int t    = threadIdx.x;
    const int lane = t & 63;
    const int wid  = t >> 6;
    const int lg   = blockIdx.x & (L_DIM / LG - 1);  // label group 0..63
    const int b    = blockIdx.x >> 6;                // batch row 0..127

    const size_t doff =
        (size_t)b * (L_DIM * I_DIM / 4) + (size_t)lg * (LG * I_DIM / 4);
    const size_t woff = (size_t)lg * (LG * I_DIM / 4);

    // one full streaming pass: 8 doc loads (nt) + 8 W loads + 32 FMA
    auto pass = [&](float (&acc)[LG]) {
        const float* docv = doc;
        const float* Wv   = W;
        // launder: make base pointers opaque so passes can't be merged
        asm volatile("" : "+s"(docv), "+s"(Wv));
        const vfloat4* dp = (const vfloat4*)docv + doff;
        const vfloat4* wp = (const vfloat4*)Wv + woff;
        vfloat4 d[LG], w[LG];
#pragma unroll
        for (int k = 0; k < LG; ++k)
            d[k] = __builtin_nontemporal_load(dp + k * 256 + t);
#pragma unroll
        for (int k = 0; k < LG; ++k) w[k] = wp[k * 256 + t];
#pragma unroll
        for (int k = 0; k < LG; ++k) {
            float a = d[k].x * w[k].x;
            a = fmaf(d[k].y, w[k].y, a);
            a = fmaf(d[k].z, w[k].z, a);
            a = fmaf(d[k].w, w[k].w, a);
            acc[k] = a;
        }
    };

    float a0[LG], a1[LG], a2[LG], a3[LG];
    pass(a0);
    pass(a1);
    pass(a2);
    pass(a3);

    float acc[LG];
#pragma unroll
    for (int k = 0; k < LG; ++k)
        acc[k] = ((a0[k] + a1[k]) + (a2[k] + a3[k])) * 0.25f;

    // ---- folded butterfly: lane 8m ends up holding wave-sum of row m ----
    const bool hi5 = (lane & 32) != 0;
    float r[4];
#pragma unroll
    for (int i = 0; i < 4; ++i) {
        const float mine = hi5 ? acc[i + 4] : acc[i];
        const float send = hi5 ? acc[i] : acc[i + 4];
        r[i] = mine + __shfl_xor(send, 32, 64);
    }
    const bool hi4 = (lane & 16) != 0;
    float s2[2];
#pragma unroll
    for (int i = 0; i < 2; ++i) {
        const float mine = hi4 ? r[i + 2] : r[i];
        const float send = hi4 ? r[i] : r[i + 2];
        s2[i] = mine + __shfl_xor(send, 16, 64);
    }
    const bool hi3 = (lane & 8) != 0;
    float s0;
    {
        const float mine = hi3 ? s2[1] : s2[0];
        const float send = hi3 ? s2[0] : s2[1];
        s0 = mine + __shfl_xor(send, 8, 64);
    }
    s0 += __shfl_xor(s0, 4, 64);
    s0 += __shfl_xor(s0, 2, 64);
    s0 += __shfl_xor(s0, 1, 64);

    // ---- cross-wave combine: 8 rows x 4 waves = 32 partials in LDS ----
    __shared__ float part[LG][4];
    if ((lane & 7) == 0) part[lane >> 3][wid] = s0;
    __syncthreads();

    if (t < 32) {
        const int m = t >> 2;   // row within group
        const int wv = t & 3;   // wave partial
        float v = part[m][wv];
        v += __shfl_xor(v, 1, 64);
        v += __shfl_xor(v, 2, 64);
        if (wv == 0) {
            const int l = lg * LG + m;
            const float z = v + bias[l];
            out[(size_t)b * L_DIM + l] = 1.0f / (1.0f + __expf(-z));
        }
    }
}

extern "C" void kernel_launch(void* const* d_in, const int* in_sizes, int n_in,
                              void* d_out, int out_size, void* d_ws, size_t ws_size,
                              hipStream_t stream) {
    const float* doc  = (const float*)d_in[0];  // (128, 512, 1024)
    const float* W    = (const float*)d_in[1];  // (512, 1024)
    const float* bias = (const float*)d_in[2];  // (512,)
    float* out = (float*)d_out;                 // (128, 512)

    const int blocks = B_DIM * (L_DIM / LG);  // 8192
    labelwise_mlc_kernel<<<blocks, 256, 0, stream>>>(doc, W, bias, out);
}

// Round 5
// 330.648 us; speedup vs baseline: 1.3498x; 1.3498x over previous
//
#include <hip/hip_runtime.h>

// LabelWiseMLC: out[b,l] = sigmoid(dot(doc_rep[b,l,:], W[l,:]) + bias[l])
// B=128, L=512, I=1024, fp32. doc (268 MB) streamed once.
//
// FINAL (restored v2, measured 330.3 us graded).
// Forensic conclusion (R4, 4x-repeat dispatch with direct counters):
//   graded dur = kernel + ~285 us FIXED harness overhead (1-GiB poison
//   fill ~161 us @6.6 TB/s + restores/gaps). Reconstructed kernel times:
//   v1 47us / v2 45us / v3 49us -> all ~90% of the 6.3 TB/s achievable
//   HBM ceiling (268 MB doc / 45 us = 5.9 TB/s). Every structural
//   variant nulled because the kernel was ALREADY at the roofline; the
//   graded number is dominated by harness cost no kernel can remove.
//   Remaining kernel headroom (~45 -> 43 us) is ~1% of graded dur, inside
//   the observed 330-352 us noise band.
//
// Structure: label-stationary waves. Each wave owns one label l and 8
// batch rows. W[l] (4 KiB) loaded once into 16 VGPRs, reused across the
// 8 dot products (W traffic 32 MB total, L2/L3-served). doc loads are
// nontemporal (zero reuse; v4 ablation showed removing nt costs ~20 us
// via L3 pollution). Streaming phase is loads+FMA only; all cross-lane
// reduction deferred: folded butterfly (10 shfl_xor for all 8 rows;
// row-sum m lands on lane 8m) -> single 8-lane store.

#define B_DIM 128
#define L_DIM 512
#define I_DIM 1024
#define WPB 8    // batch rows per wave
#define DEPTH 4  // pipelined rows in flight

typedef float vfloat4 __attribute__((ext_vector_type(4)));

__global__ __launch_bounds__(256, 4) void labelwise_mlc_kernel(
    const float* __restrict__ doc,   // (B, L, I)
    const float* __restrict__ W,     // (L, I)
    const float* __restrict__ bias,  // (L,)
    float* __restrict__ out)         // (B, L)
{
    const int wave = (blockIdx.x * 256 + threadIdx.x) >> 6;  // 0..8191
    const int lane = threadIdx.x & 63;
    const int l  = wave & (L_DIM - 1);          // label index
    const int b0 = (wave >> 9) * WPB;           // starting batch row

    // W[l] fragment: lane i holds float4s at {i, 64+i, 128+i, 192+i}
    const vfloat4* __restrict__ wp = (const vfloat4*)(W + (size_t)l * I_DIM);
    vfloat4 w[4];
#pragma unroll
    for (int k = 0; k < 4; ++k) w[k] = wp[lane + 64 * k];
    const float bl = bias[l];

    const float* dbase = doc + ((size_t)b0 * L_DIM + l) * I_DIM;
    const size_t rstride = (size_t)L_DIM * I_DIM;  // floats between b rows

    // ---- streaming phase: pure loads + per-lane FMA partials ----
    vfloat4 buf[DEPTH][4];
#pragma unroll
    for (int j = 0; j < DEPTH; ++j) {
        const vfloat4* dp = (const vfloat4*)(dbase + (size_t)j * rstride);
#pragma unroll
        for (int k = 0; k < 4; ++k)
            buf[j][k] = __builtin_nontemporal_load(dp + lane + 64 * k);
    }

    float acc[WPB];
#pragma unroll
    for (int j = 0; j < WPB; ++j) {
        const int s = j & (DEPTH - 1);  // compile-time after unroll
        float a0 = 0.0f, a1 = 0.0f;     // two chains: halve FMA latency
#pragma unroll
        for (int k = 0; k < 2; ++k) {
            a0 = fmaf(buf[s][k].x, w[k].x, a0);
            a0 = fmaf(buf[s][k].y, w[k].y, a0);
            a0 = fmaf(buf[s][k].z, w[k].z, a0);
            a0 = fmaf(buf[s][k].w, w[k].w, a0);
        }
#pragma unroll
        for (int k = 2; k < 4; ++k) {
            a1 = fmaf(buf[s][k].x, w[k].x, a1);
            a1 = fmaf(buf[s][k].y, w[k].y, a1);
            a1 = fmaf(buf[s][k].z, w[k].z, a1);
            a1 = fmaf(buf[s][k].w, w[k].w, a1);
        }
        acc[j] = a0 + a1;
        if (j + DEPTH < WPB) {  // refill slot s with row j+DEPTH
            const vfloat4* dp =
                (const vfloat4*)(dbase + (size_t)(j + DEPTH) * rstride);
#pragma unroll
            for (int k = 0; k < 4; ++k)
                buf[s][k] = __builtin_nontemporal_load(dp + lane + 64 * k);
        }
    }

    // ---- folded multi-row butterfly reduction: 10 shuffles total ----
    const bool hi5 = (lane & 32) != 0;
    float r[4];
#pragma unroll
    for (int i = 0; i < 4; ++i) {
        const float mine = hi5 ? acc[i + 4] : acc[i];
        const float send = hi5 ? acc[i] : acc[i + 4];
        r[i] = mine + __shfl_xor(send, 32, 64);
    }
    const bool hi4 = (lane & 16) != 0;
    float s2[2];
#pragma unroll
    for (int i = 0; i < 2; ++i) {
        const float mine = hi4 ? r[i + 2] : r[i];
        const float send = hi4 ? r[i] : r[i + 2];
        s2[i] = mine + __shfl_xor(send, 16, 64);
    }
    const bool hi3 = (lane & 8) != 0;
    float s0;
    {
        const float mine = hi3 ? s2[1] : s2[0];
        const float send = hi3 ? s2[0] : s2[1];
        s0 = mine + __shfl_xor(send, 8, 64);
    }
    s0 += __shfl_xor(s0, 4, 64);
    s0 += __shfl_xor(s0, 2, 64);
    s0 += __shfl_xor(s0, 1, 64);

    // lane 8m holds S[j=m] (m = 4*bit5 + 2*bit4 + 1*bit3 = lane>>3).
    if ((lane & 7) == 0) {
        const int j = lane >> 3;
        const float v = s0 + bl;
        out[(size_t)(b0 + j) * L_DIM + l] = 1.0f / (1.0f + __expf(-v));
    }
}

extern "C" void kernel_launch(void* const* d_in, const int* in_sizes, int n_in,
                              void* d_out, int out_size, void* d_ws, size_t ws_size,
                              hipStream_t stream) {
    const float* doc  = (const float*)d_in[0];  // (128, 512, 1024)
    const float* W    = (const float*)d_in[1];  // (512, 1024)
    const float* bias = (const float*)d_in[2];  // (512,)
    float* out = (float*)d_out;                 // (128, 512)

    // 8192 waves: 512 labels x 16 wave-groups (8 batch rows each)
    const int blocks = (L_DIM * (B_DIM / WPB)) / 4;  // 2048
    labelwise_mlc_kernel<<<blocks, 256, 0, stream>>>(doc, W, bias, out);
}